// Round 1
// baseline (978.254 us; speedup 1.0000x reference)
//
#include <hip/hip_runtime.h>
#include <math.h>

#define CDIV(a,b) (((a)+(b)-1)/(b))

__device__ __forceinline__ float lrelu(float v){ return v > 0.f ? v : 0.2f*v; }

// ---------------- CSR build (by dst) ----------------
__global__ void k_count_deg(const int* __restrict__ edst, int E, int ET, int* __restrict__ off){
  int e = blockIdx.x*blockDim.x + threadIdx.x;
  if (e >= ET) return;
  int d = (e < E) ? edst[e] : (e - E);   // self-loops appended at the end
  atomicAdd(&off[d+1], 1);
}

// single-block scan: off[1..n] counts -> inclusive prefix; cursor[i] = segment start
__global__ void k_scan(int* __restrict__ off, int* __restrict__ cursor, int n){
  __shared__ int sums[256];
  int t = threadIdx.x;
  int chunk = CDIV(n,256);
  int beg = 1 + t*chunk;
  int end = min(1 + (t+1)*chunk, n+1);
  int s = 0;
  for (int i=beg;i<end;i++) s += off[i];
  sums[t] = s;
  __syncthreads();
  if (t==0){ int a=0; for (int j=0;j<256;j++){ int v=sums[j]; sums[j]=a; a+=v; } }
  __syncthreads();
  int run = sums[t];
  if (t==0) cursor[0] = 0;
  for (int i=beg;i<end;i++){ run += off[i]; off[i] = run; if (i < n) cursor[i] = run; }
}

__global__ void k_fill(const int* __restrict__ edst, int E, int ET,
                       int* __restrict__ cursor, int* __restrict__ adj){
  int e = blockIdx.x*blockDim.x + threadIdx.x;
  if (e >= ET) return;
  int d = (e < E) ? edst[e] : (e - E);
  int pos = atomicAdd(&cursor[d], 1);
  adj[pos] = e;
}

// ---------------- fp32 GEMM: C[M, 2*Npm] = A[M,K] @ [B0 | B1]  ----------------
// BM=64, BN=64, BK=16, 256 threads, 4x4 per thread
__global__ __launch_bounds__(256) void gemm_dual(
    const float* __restrict__ A, int M, int K,
    const float* __restrict__ B0, const float* __restrict__ B1, int Npm,
    float* __restrict__ C, int ldc)
{
  const int BM=64, BN=64, BK=16;
  __shared__ float As[BK][BM+4];
  __shared__ float Bs[BK][BN];
  int tid = threadIdx.x;
  int row0 = blockIdx.x*BM;
  int colbase = blockIdx.y*BN;
  const float* B = (colbase < Npm) ? B0 : B1;
  int colInMat = colbase % Npm;

  int ty = tid >> 4, tx = tid & 15;
  int ar = tid >> 2;          // 0..63 (A row within tile)
  int ak = (tid & 3) << 2;    // 0,4,8,12 (A k within tile)
  int br = tid >> 4;          // 0..15 (B k within tile)
  int bc = (tid & 15) << 2;   // 0..60 (B col within tile)

  float acc[4][4] = {};

  for (int kt = 0; kt < K; kt += BK) {
    float4 a4 = make_float4(0.f,0.f,0.f,0.f);
    if (row0 + ar < M)
      a4 = *reinterpret_cast<const float4*>(A + (size_t)(row0+ar)*K + kt + ak);
    As[ak+0][ar] = a4.x; As[ak+1][ar] = a4.y; As[ak+2][ar] = a4.z; As[ak+3][ar] = a4.w;
    float4 b4 = *reinterpret_cast<const float4*>(B + (size_t)(kt+br)*Npm + colInMat + bc);
    *reinterpret_cast<float4*>(&Bs[br][bc]) = b4;
    __syncthreads();
    #pragma unroll
    for (int k=0;k<BK;k++) {
      float a[4], b[4];
      #pragma unroll
      for (int i=0;i<4;i++) a[i] = As[k][ty*4+i];
      #pragma unroll
      for (int j=0;j<4;j++) b[j] = Bs[k][tx*4+j];
      #pragma unroll
      for (int i=0;i<4;i++)
        #pragma unroll
        for (int j=0;j<4;j++) acc[i][j] = fmaf(a[i], b[j], acc[i][j]);
    }
    __syncthreads();
  }
  #pragma unroll
  for (int i=0;i<4;i++){
    int r = row0 + ty*4 + i;
    if (r < M) {
      #pragma unroll
      for (int j=0;j<4;j++)
        C[(size_t)r*ldc + colbase + tx*4 + j] = acc[i][j];
    }
  }
}

// ---------------- layer-1 edge logits: lg1[e][h] ----------------
__global__ __launch_bounds__(256) void k_logits1(
    const int* __restrict__ esrc, const int* __restrict__ edst, int E, int ET,
    const float* __restrict__ H1, const float* __restrict__ att1, float* __restrict__ lg1)
{
  int tid = blockIdx.x*blockDim.x + threadIdx.x;
  if (tid >= ET*8) return;
  int e = tid >> 3, h = tid & 7;
  int s, d;
  if (e < E) { s = esrc[e]; d = edst[e]; } else { s = d = e - E; }
  const float4* xl = reinterpret_cast<const float4*>(H1 + (size_t)s*256 + h*16);
  const float4* xr = reinterpret_cast<const float4*>(H1 + (size_t)d*256 + 128 + h*16);
  const float4* at = reinterpret_cast<const float4*>(att1 + h*16);
  float acc = 0.f;
  #pragma unroll
  for (int q=0;q<4;q++){
    float4 a = xl[q], b = xr[q], w = at[q];
    acc = fmaf(w.x, lrelu(a.x+b.x), acc);
    acc = fmaf(w.y, lrelu(a.y+b.y), acc);
    acc = fmaf(w.z, lrelu(a.z+b.z), acc);
    acc = fmaf(w.w, lrelu(a.w+b.w), acc);
  }
  lg1[tid] = acc;
}

// ---------------- layer-1 node softmax + aggregate + bias + elu ----------------
__global__ __launch_bounds__(128) void k_agg1(
    const int* __restrict__ off, const int* __restrict__ adj,
    const int* __restrict__ esrc, int E,
    const float* __restrict__ H1, float* __restrict__ lg1,
    const float* __restrict__ b1, float* __restrict__ out1)
{
  int i = blockIdx.x;
  int begin = off[i], end = off[i+1];
  int deg = end - begin;
  if (threadIdx.x < 64){
    int l = threadIdx.x;
    int hh = l >> 3, k0 = l & 7;          // 8 heads x 8 edge-lanes
    float lm = -INFINITY;
    for (int k=k0;k<deg;k+=8) lm = fmaxf(lm, lg1[(size_t)adj[begin+k]*8 + hh]);
    lm = fmaxf(lm, __shfl_xor(lm,1,64));
    lm = fmaxf(lm, __shfl_xor(lm,2,64));
    lm = fmaxf(lm, __shfl_xor(lm,4,64));
    float ls = 0.f;
    for (int k=k0;k<deg;k+=8) ls += expf(lg1[(size_t)adj[begin+k]*8 + hh] - lm);
    ls += __shfl_xor(ls,1,64);
    ls += __shfl_xor(ls,2,64);
    ls += __shfl_xor(ls,4,64);
    float inv = 1.f/(ls + 1e-16f);
    // rewrite logits in place as alpha (each edge owned by exactly one dst block)
    for (int k=k0;k<deg;k+=8){
      size_t idx = (size_t)adj[begin+k]*8 + hh;
      lg1[idx] = expf(lg1[idx]-lm)*inv;
    }
  }
  __syncthreads();
  int h = threadIdx.x >> 4, d = threadIdx.x & 15;
  float acc = 0.f;
  for (int k=0;k<deg;k++){
    int e = adj[begin+k];
    int s = (e < E) ? esrc[e] : (e - E);
    acc += lg1[(size_t)e*8 + h] * H1[(size_t)s*256 + h*16 + d];
  }
  float o = acc + b1[threadIdx.x];
  out1[(size_t)i*128 + threadIdx.x] = o > 0.f ? o : expm1f(o);   // elu
}

// ---------------- layer-2 edge logits: lg2[e] ----------------
__global__ __launch_bounds__(256) void k_logits2(
    const int* __restrict__ esrc, const int* __restrict__ edst, int E, int ET,
    const float* __restrict__ H2, const float* __restrict__ att2, float* __restrict__ lg2)
{
  int tid = blockIdx.x*blockDim.x + threadIdx.x;
  if (tid >= ET*8) return;
  int e = tid >> 3, p = tid & 7;          // 8 threads per edge, 8 dims each
  int s, d;
  if (e < E) { s = esrc[e]; d = edst[e]; } else { s = d = e - E; }
  const float4* xl = reinterpret_cast<const float4*>(H2 + (size_t)s*128 + p*8);
  const float4* xr = reinterpret_cast<const float4*>(H2 + (size_t)d*128 + 64 + p*8);
  const float4* at = reinterpret_cast<const float4*>(att2 + p*8);
  float acc = 0.f;
  #pragma unroll
  for (int q=0;q<2;q++){
    float4 a = xl[q], b = xr[q], w = at[q];
    acc = fmaf(w.x, lrelu(a.x+b.x), acc);
    acc = fmaf(w.y, lrelu(a.y+b.y), acc);
    acc = fmaf(w.z, lrelu(a.z+b.z), acc);
    acc = fmaf(w.w, lrelu(a.w+b.w), acc);
  }
  acc += __shfl_xor(acc,1,64);
  acc += __shfl_xor(acc,2,64);
  acc += __shfl_xor(acc,4,64);
  if (p == 0) lg2[e] = acc;
}

// ---------------- layer-2 node softmax + aggregate + bias + log_softmax ----------------
__global__ __launch_bounds__(64) void k_agg2(
    const int* __restrict__ off, const int* __restrict__ adj,
    const int* __restrict__ esrc, int E,
    const float* __restrict__ H2, const float* __restrict__ lg2,
    const float* __restrict__ b2, float* __restrict__ out)
{
  __shared__ float sm_alpha[64];
  __shared__ int   sm_src[64];
  int i = blockIdx.x;
  int begin = off[i], end = off[i+1];
  int deg = end - begin;
  int lane = threadIdx.x;

  float lm = -INFINITY;
  for (int k=lane;k<deg;k+=64) lm = fmaxf(lm, lg2[adj[begin+k]]);
  #pragma unroll
  for (int m=1;m<64;m<<=1) lm = fmaxf(lm, __shfl_xor(lm,m,64));
  float ls = 0.f;
  for (int k=lane;k<deg;k+=64) ls += expf(lg2[adj[begin+k]] - lm);
  #pragma unroll
  for (int m=1;m<64;m<<=1) ls += __shfl_xor(ls,m,64);
  float inv = 1.f/(ls + 1e-16f);

  float acc = 0.f;
  for (int base=0;base<deg;base+=64){
    int cnt = min(64, deg-base);
    if (lane < cnt){
      int e = adj[begin+base+lane];
      sm_src[lane]   = (e < E) ? esrc[e] : (e - E);
      sm_alpha[lane] = expf(lg2[e]-lm)*inv;
    }
    __syncthreads();
    for (int j=0;j<cnt;j++) acc += sm_alpha[j] * H2[(size_t)sm_src[j]*128 + lane];
    __syncthreads();
  }
  float o = acc + b2[lane];
  float mx = o;
  #pragma unroll
  for (int m=1;m<64;m<<=1) mx = fmaxf(mx, __shfl_xor(mx,m,64));
  float se = expf(o - mx);
  #pragma unroll
  for (int m=1;m<64;m<<=1) se += __shfl_xor(se,m,64);
  out[(size_t)i*64 + lane] = o - mx - logf(se);
}

extern "C" void kernel_launch(void* const* d_in, const int* in_sizes, int n_in,
                              void* d_out, int out_size, void* d_ws, size_t ws_size,
                              hipStream_t stream)
{
  const float* x    = (const float*)d_in[0];
  const int*   ei   = (const int*)  d_in[1];
  const float* Wl1  = (const float*)d_in[2];
  const float* Wr1  = (const float*)d_in[3];
  const float* att1 = (const float*)d_in[4];
  const float* b1   = (const float*)d_in[5];
  const float* Wl2  = (const float*)d_in[6];
  const float* Wr2  = (const float*)d_in[7];
  const float* att2 = (const float*)d_in[8];
  const float* b2   = (const float*)d_in[9];
  float* out = (float*)d_out;

  const int DIN = 512;
  int N  = in_sizes[0] / DIN;     // 50000
  int E  = in_sizes[1] / 2;       // 800000
  int ET = E + N;                 // + self loops
  const int* esrc = ei;
  const int* edst = ei + E;

  char* p = (char*)d_ws;
  auto walloc = [&](size_t bytes)->void*{
    void* r = (void*)p; p += (bytes + 255) & ~(size_t)255; return r;
  };
  float* H1   = (float*)walloc((size_t)N*256*4);   // [xl1 | xr1]
  float* out1 = (float*)walloc((size_t)N*128*4);   // post-elu layer1 output
  float* H2   = (float*)walloc((size_t)N*128*4);   // [xl2 | xr2]
  float* lg1  = (float*)walloc((size_t)ET*8*4);    // logits -> alpha (in place)
  float* lg2  = (float*)walloc((size_t)ET*4);
  int* off    = (int*)walloc((size_t)(N+1)*4);
  int* cursor = (int*)walloc((size_t)N*4);
  int* adj    = (int*)walloc((size_t)ET*4);

  // CSR build
  hipMemsetAsync(off, 0, (size_t)(N+1)*4, stream);
  k_count_deg<<<CDIV(ET,256),256,0,stream>>>(edst, E, ET, off);
  k_scan<<<1,256,0,stream>>>(off, cursor, N);
  k_fill<<<CDIV(ET,256),256,0,stream>>>(edst, E, ET, cursor, adj);

  // Layer 1
  dim3 g1(CDIV(N,64), 4);
  gemm_dual<<<g1,256,0,stream>>>(x, N, 512, Wl1, Wr1, 128, H1, 256);
  k_logits1<<<CDIV(ET*8,256),256,0,stream>>>(esrc, edst, E, ET, H1, att1, lg1);
  k_agg1<<<N,128,0,stream>>>(off, adj, esrc, E, H1, lg1, b1, out1);

  // Layer 2
  dim3 g2(CDIV(N,64), 2);
  gemm_dual<<<g2,256,0,stream>>>(out1, N, 128, Wl2, Wr2, 64, H2, 128);
  k_logits2<<<CDIV(ET*8,256),256,0,stream>>>(esrc, edst, E, ET, H2, att2, lg2);
  k_agg2<<<N,64,0,stream>>>(off, adj, esrc, E, H2, lg2, b2, out);
}

// Round 2
// 850.108 us; speedup vs baseline: 1.1507x; 1.1507x over previous
//
#include <hip/hip_runtime.h>
#include <math.h>

#define CDIV(a,b) (((a)+(b)-1)/(b))

typedef __bf16 bf16x8 __attribute__((ext_vector_type(8)));
typedef float  f32x4  __attribute__((ext_vector_type(4)));

__device__ __forceinline__ float lrelu(float v){ return v > 0.f ? v : 0.2f*v; }

// ---------------- CSR build (by dst) ----------------
__global__ void k_count_deg(const int* __restrict__ edst, int E, int ET, int* __restrict__ off){
  int e = blockIdx.x*blockDim.x + threadIdx.x;
  if (e >= ET) return;
  int d = (e < E) ? edst[e] : (e - E);   // self-loops appended at the end
  atomicAdd(&off[d+1], 1);
}

__global__ void k_scan(int* __restrict__ off, int* __restrict__ cursor, int n){
  __shared__ int sums[256];
  int t = threadIdx.x;
  int chunk = CDIV(n,256);
  int beg = 1 + t*chunk;
  int end = min(1 + (t+1)*chunk, n+1);
  int s = 0;
  for (int i=beg;i<end;i++) s += off[i];
  sums[t] = s;
  __syncthreads();
  if (t==0){ int a=0; for (int j=0;j<256;j++){ int v=sums[j]; sums[j]=a; a+=v; } }
  __syncthreads();
  int run = sums[t];
  if (t==0) cursor[0] = 0;
  for (int i=beg;i<end;i++){ run += off[i]; off[i] = run; if (i < n) cursor[i] = run; }
}

__global__ void k_fill(const int* __restrict__ edst, int E, int ET,
                       int* __restrict__ cursor, int* __restrict__ adj){
  int e = blockIdx.x*blockDim.x + threadIdx.x;
  if (e >= ET) return;
  int d = (e < E) ? edst[e] : (e - E);
  int pos = atomicAdd(&cursor[d], 1);
  adj[pos] = e;
}

// ---------------- prep: fp32 -> bf16 convert ----------------
__global__ void k_cvt_bf16(const float* __restrict__ in, __bf16* __restrict__ out, int n4){
  int i = blockIdx.x*blockDim.x + threadIdx.x;
  if (i >= n4) return;
  float4 v = reinterpret_cast<const float4*>(in)[i];
  __bf16 o[4] = {(__bf16)v.x,(__bf16)v.y,(__bf16)v.z,(__bf16)v.w};
  *reinterpret_cast<ushort4*>(out + (size_t)i*4) =
      *reinterpret_cast<ushort4*>(o);
}

// ---------------- prep: Wt[c][k] = concat(Wl,Wr)[k][c] as bf16 ----------------
__global__ void k_prep_wt(const float* __restrict__ Wl, const float* __restrict__ Wr,
                          __bf16* __restrict__ Wt, int K, int Nh){
  int c = blockIdx.x, k = threadIdx.x;
  float v = (c < Nh) ? Wl[(size_t)k*Nh + c] : Wr[(size_t)k*Nh + (c - Nh)];
  Wt[(size_t)c*K + k] = (__bf16)v;
}

// ---------------- bf16 MFMA GEMM: C[M, NT*16] = A[M,K] @ Bt^T ----------------
// Bt is [NT*16, K] row-major (i.e., B transposed). 256 threads = 4 waves,
// each wave owns 16 rows; NT col-tiles of 16. A/B frags use a mutually
// consistent k-order (g*8+j); C/D map col=lane&15, row=(lane>>4)*4+reg.
template<int NT>
__global__ __launch_bounds__(256) void gemm_bf16(
    const __bf16* __restrict__ A, int M, int K,
    const __bf16* __restrict__ Bt, __bf16* __restrict__ C)
{
  int tid = threadIdx.x;
  int wave = tid >> 6, lane = tid & 63;
  int g = lane >> 4, r16 = lane & 15;
  int arow = blockIdx.x*64 + wave*16 + r16;
  int arow_c = min(arow, M-1);
  f32x4 acc[NT];
  #pragma unroll
  for (int t=0;t<NT;t++) acc[t] = (f32x4){0.f,0.f,0.f,0.f};
  for (int kk=0; kk<K; kk+=32){
    bf16x8 a = *reinterpret_cast<const bf16x8*>(A + (size_t)arow_c*K + kk + g*8);
    #pragma unroll
    for (int t=0;t<NT;t++){
      bf16x8 b = *reinterpret_cast<const bf16x8*>(Bt + (size_t)(t*16 + r16)*K + kk + g*8);
      acc[t] = __builtin_amdgcn_mfma_f32_16x16x32_bf16(a, b, acc[t], 0, 0, 0);
    }
  }
  int crow0 = blockIdx.x*64 + wave*16 + g*4;
  #pragma unroll
  for (int t=0;t<NT;t++){
    #pragma unroll
    for (int r=0;r<4;r++){
      int row = crow0 + r;
      if (row < M) C[(size_t)row*(NT*16) + t*16 + r16] = (__bf16)acc[t][r];
    }
  }
}

// ---------------- layer 1 fused: logits + online softmax + aggregate + elu ----
// one block (128 thr = 8 heads x 16 dims) per dst node; no inter-wave comm
__global__ __launch_bounds__(128) void k_fused1(
    const int* __restrict__ off, const int* __restrict__ adj,
    const int* __restrict__ esrc, int E,
    const __bf16* __restrict__ H1, const float* __restrict__ att1,
    const float* __restrict__ b1, __bf16* __restrict__ out1)
{
  int i = blockIdx.x;
  int tid = threadIdx.x;
  int begin = off[i], deg = off[i+1] - begin;
  float xr = (float)H1[(size_t)i*256 + 128 + tid];
  float aw = att1[tid];
  float m = -INFINITY, s = 0.f, acc = 0.f;

  int e0 = adj[begin];
  int s0 = (e0 < E) ? esrc[e0] : (e0 - E);
  float xl = (float)H1[(size_t)s0*256 + tid];
  for (int k=0;k<deg;k++){
    float xl_cur = xl;
    if (k+1 < deg){
      int e1 = adj[begin+k+1];
      int s1 = (e1 < E) ? esrc[e1] : (e1 - E);
      xl = (float)H1[(size_t)s1*256 + tid];
    }
    float p = aw * lrelu(xl_cur + xr);
    p += __shfl_xor(p,1,64); p += __shfl_xor(p,2,64);
    p += __shfl_xor(p,4,64); p += __shfl_xor(p,8,64);   // head-wide logit
    float mn = fmaxf(m, p);
    float c = __expf(m - mn);      // first iter: exp(-inf)=0
    float w = __expf(p - mn);
    s   = s*c + w;
    acc = acc*c + w*xl_cur;
    m = mn;
  }
  float o = acc/(s + 1e-16f) + b1[tid];
  out1[(size_t)i*128 + tid] = (__bf16)(o > 0.f ? o : expm1f(o));
}

// ---------------- layer 2 fused: logits + softmax + aggregate + log_softmax ---
// one wave per dst node, thread d owns output dim d
__global__ __launch_bounds__(64) void k_fused2(
    const int* __restrict__ off, const int* __restrict__ adj,
    const int* __restrict__ esrc, int E,
    const __bf16* __restrict__ H2, const float* __restrict__ att2,
    const float* __restrict__ b2, float* __restrict__ out)
{
  int i = blockIdx.x, d = threadIdx.x;
  int begin = off[i], deg = off[i+1] - begin;
  float xr = (float)H2[(size_t)i*128 + 64 + d];
  float aw = att2[d];
  float m = -INFINITY, s = 0.f, acc = 0.f;

  int e0 = adj[begin];
  int s0 = (e0 < E) ? esrc[e0] : (e0 - E);
  float xl = (float)H2[(size_t)s0*128 + d];
  for (int k=0;k<deg;k++){
    float xl_cur = xl;
    if (k+1 < deg){
      int e1 = adj[begin+k+1];
      int s1 = (e1 < E) ? esrc[e1] : (e1 - E);
      xl = (float)H2[(size_t)s1*128 + d];
    }
    float p = aw * lrelu(xl_cur + xr);
    #pragma unroll
    for (int mm=1;mm<64;mm<<=1) p += __shfl_xor(p,mm,64);
    float mn = fmaxf(m, p);
    float c = __expf(m - mn);
    float w = __expf(p - mn);
    s   = s*c + w;
    acc = acc*c + w*xl_cur;
    m = mn;
  }
  float o = acc/(s + 1e-16f) + b2[d];
  // log_softmax across the 64 lanes
  float mx = o;
  #pragma unroll
  for (int mm=1;mm<64;mm<<=1) mx = fmaxf(mx, __shfl_xor(mx,mm,64));
  float se = __expf(o - mx);
  #pragma unroll
  for (int mm=1;mm<64;mm<<=1) se += __shfl_xor(se,mm,64);
  out[(size_t)i*64 + d] = o - mx - __logf(se);
}

extern "C" void kernel_launch(void* const* d_in, const int* in_sizes, int n_in,
                              void* d_out, int out_size, void* d_ws, size_t ws_size,
                              hipStream_t stream)
{
  const float* x    = (const float*)d_in[0];
  const int*   ei   = (const int*)  d_in[1];
  const float* Wl1  = (const float*)d_in[2];
  const float* Wr1  = (const float*)d_in[3];
  const float* att1 = (const float*)d_in[4];
  const float* b1   = (const float*)d_in[5];
  const float* Wl2  = (const float*)d_in[6];
  const float* Wr2  = (const float*)d_in[7];
  const float* att2 = (const float*)d_in[8];
  const float* b2   = (const float*)d_in[9];
  float* out = (float*)d_out;

  const int DIN = 512;
  int N  = in_sizes[0] / DIN;     // 50000
  int E  = in_sizes[1] / 2;       // 800000
  int ET = E + N;                 // + self loops
  const int* esrc = ei;
  const int* edst = ei + E;

  char* p = (char*)d_ws;
  auto walloc = [&](size_t bytes)->void*{
    void* r = (void*)p; p += (bytes + 255) & ~(size_t)255; return r;
  };
  __bf16* xb   = (__bf16*)walloc((size_t)N*DIN*2);  // x in bf16
  __bf16* Wt1  = (__bf16*)walloc((size_t)256*512*2);
  __bf16* Wt2  = (__bf16*)walloc((size_t)128*128*2);
  __bf16* H1   = (__bf16*)walloc((size_t)N*256*2);  // [xl1 | xr1]
  __bf16* out1 = (__bf16*)walloc((size_t)N*128*2);  // post-elu layer1 output
  __bf16* H2   = (__bf16*)walloc((size_t)N*128*2);  // [xl2 | xr2]
  int* off    = (int*)walloc((size_t)(N+1)*4);
  int* cursor = (int*)walloc((size_t)N*4);
  int* adj    = (int*)walloc((size_t)ET*4);

  // CSR build
  hipMemsetAsync(off, 0, (size_t)(N+1)*4, stream);
  k_count_deg<<<CDIV(ET,256),256,0,stream>>>(edst, E, ET, off);
  k_scan<<<1,256,0,stream>>>(off, cursor, N);
  k_fill<<<CDIV(ET,256),256,0,stream>>>(edst, E, ET, cursor, adj);

  // prep
  int n4 = N*DIN/4;
  k_cvt_bf16<<<CDIV(n4,256),256,0,stream>>>(x, xb, n4);
  k_prep_wt<<<256,512,0,stream>>>(Wl1, Wr1, Wt1, 512, 128);
  k_prep_wt<<<128,128,0,stream>>>(Wl2, Wr2, Wt2, 128, 64);

  // Layer 1
  gemm_bf16<16><<<CDIV(N,64),256,0,stream>>>(xb, N, 512, Wt1, H1);
  k_fused1<<<N,128,0,stream>>>(off, adj, esrc, E, H1, att1, b1, out1);

  // Layer 2
  gemm_bf16<8><<<CDIV(N,64),256,0,stream>>>(out1, N, 128, Wt2, H2);
  k_fused2<<<N,64,0,stream>>>(off, adj, esrc, E, H2, att2, b2, out);
}

// Round 3
// 729.332 us; speedup vs baseline: 1.3413x; 1.1656x over previous
//
#include <hip/hip_runtime.h>
#include <math.h>

#define CDIV(a,b) (((a)+(b)-1)/(b))

typedef __bf16 bf16x8 __attribute__((ext_vector_type(8)));
typedef float  f32x4  __attribute__((ext_vector_type(4)));

__device__ __forceinline__ float lrelu(float v){ return v > 0.f ? v : 0.2f*v; }

// ---------------- CSR build (by dst) ----------------
__global__ void k_count_deg(const int* __restrict__ edst, int E, int ET, int* __restrict__ off){
  int e = blockIdx.x*blockDim.x + threadIdx.x;
  if (e >= ET) return;
  int d = (e < E) ? edst[e] : (e - E);   // self-loops appended at the end
  atomicAdd(&off[d+1], 1);
}

__global__ void k_scan(int* __restrict__ off, int* __restrict__ cursor, int n){
  __shared__ int sums[256];
  int t = threadIdx.x;
  int chunk = CDIV(n,256);
  int beg = 1 + t*chunk;
  int end = min(1 + (t+1)*chunk, n+1);
  int s = 0;
  for (int i=beg;i<end;i++) s += off[i];
  sums[t] = s;
  __syncthreads();
  if (t==0){ int a=0; for (int j=0;j<256;j++){ int v=sums[j]; sums[j]=a; a+=v; } }
  __syncthreads();
  int run = sums[t];
  if (t==0) cursor[0] = 0;
  for (int i=beg;i<end;i++){ run += off[i]; off[i] = run; if (i < n) cursor[i] = run; }
}

__global__ void k_fill(const int* __restrict__ edst, int E, int ET,
                       int* __restrict__ cursor, int* __restrict__ adj){
  int e = blockIdx.x*blockDim.x + threadIdx.x;
  if (e >= ET) return;
  int d = (e < E) ? edst[e] : (e - E);
  int pos = atomicAdd(&cursor[d], 1);
  adj[pos] = e;
}

// ---------------- prep: fp32 -> bf16 convert ----------------
__global__ void k_cvt_bf16(const float* __restrict__ in, __bf16* __restrict__ out, int n4){
  int i = blockIdx.x*blockDim.x + threadIdx.x;
  if (i >= n4) return;
  float4 v = reinterpret_cast<const float4*>(in)[i];
  __bf16 o[4] = {(__bf16)v.x,(__bf16)v.y,(__bf16)v.z,(__bf16)v.w};
  *reinterpret_cast<ushort4*>(out + (size_t)i*4) =
      *reinterpret_cast<ushort4*>(o);
}

// ---------------- prep: Wt[c][k] = concat(Wl,Wr)[k][c] as bf16 ----------------
__global__ void k_prep_wt(const float* __restrict__ Wl, const float* __restrict__ Wr,
                          __bf16* __restrict__ Wt, int K, int Nh){
  int c = blockIdx.x, k = threadIdx.x;
  float v = (c < Nh) ? Wl[(size_t)k*Nh + c] : Wr[(size_t)k*Nh + (c - Nh)];
  Wt[(size_t)c*K + k] = (__bf16)v;
}

// ---------------- bf16 MFMA GEMM: C[M, NT*16] = A[M,K] @ Bt^T ----------------
template<int NT>
__global__ __launch_bounds__(256) void gemm_bf16(
    const __bf16* __restrict__ A, int M, int K,
    const __bf16* __restrict__ Bt, __bf16* __restrict__ C)
{
  int tid = threadIdx.x;
  int wave = tid >> 6, lane = tid & 63;
  int g = lane >> 4, r16 = lane & 15;
  int arow = blockIdx.x*64 + wave*16 + r16;
  int arow_c = min(arow, M-1);
  f32x4 acc[NT];
  #pragma unroll
  for (int t=0;t<NT;t++) acc[t] = (f32x4){0.f,0.f,0.f,0.f};
  for (int kk=0; kk<K; kk+=32){
    bf16x8 a = *reinterpret_cast<const bf16x8*>(A + (size_t)arow_c*K + kk + g*8);
    #pragma unroll
    for (int t=0;t<NT;t++){
      bf16x8 b = *reinterpret_cast<const bf16x8*>(Bt + (size_t)(t*16 + r16)*K + kk + g*8);
      acc[t] = __builtin_amdgcn_mfma_f32_16x16x32_bf16(a, b, acc[t], 0, 0, 0);
    }
  }
  int crow0 = blockIdx.x*64 + wave*16 + g*4;
  #pragma unroll
  for (int t=0;t<NT;t++){
    #pragma unroll
    for (int r=0;r<4;r++){
      int row = crow0 + r;
      if (row < M) C[(size_t)row*(NT*16) + t*16 + r16] = (__bf16)acc[t][r];
    }
  }
}

// ---------------- layer 1 fused: chunked two-pass softmax + aggregate + elu ---
// block = dst node, 128 threads. Pass1 mapping: (e=tid>>3, h1=tid&7) — each
// thread computes one (edge,head) logit fully locally. Pass2 mapping:
// (h2=tid>>4, d=tid&15) — output dim h2*16+d == tid.
__global__ __launch_bounds__(128) void k_fused1(
    const int* __restrict__ off, const int* __restrict__ adj,
    const int* __restrict__ esrc, int E,
    const __bf16* __restrict__ H1, const float* __restrict__ att1,
    const float* __restrict__ b1, __bf16* __restrict__ out1)
{
  __shared__ __bf16 xls[16][132];   // stride 132: free reads in pass2
  __shared__ float  lgs[8][17];
  __shared__ float  ws [8][17];
  int i = blockIdx.x;
  int tid = threadIdx.x;
  int e_id = tid >> 3, h1 = tid & 7;
  int h2 = tid >> 4, d  = tid & 15;
  int begin = off[i], deg = off[i+1] - begin;

  float xr1[16], aw1[16];
  #pragma unroll
  for (int j=0;j<16;j++){
    xr1[j] = (float)H1[(size_t)i*256 + 128 + h1*16 + j];
    aw1[j] = att1[h1*16 + j];
  }

  float m_run = -INFINITY, s_run = 0.f, acc = 0.f;
  int nch = (deg + 15) >> 4;
  for (int ch=0; ch<nch; ch++){
    int base = ch*16;
    int cnt = min(16, deg - base);
    int k = base + e_id;
    // ---- pass 1: independent per-(edge,head) logits + xl staging ----
    if (e_id < cnt){
      int e = adj[begin + k];
      int s = (e < E) ? esrc[e] : (e - E);
      const __bf16* row = H1 + (size_t)s*256 + h1*16;
      bf16x8 v0 = *reinterpret_cast<const bf16x8*>(row);
      bf16x8 v1 = *reinterpret_cast<const bf16x8*>(row + 8);
      float lg = 0.f;
      #pragma unroll
      for (int j=0;j<8;j++){
        lg = fmaf(aw1[j],   lrelu((float)v0[j] + xr1[j]),   lg);
        lg = fmaf(aw1[j+8], lrelu((float)v1[j] + xr1[j+8]), lg);
      }
      lgs[h1][e_id] = lg;
      ushort4* dst = reinterpret_cast<ushort4*>(&xls[e_id][h1*16]);
      dst[0] = *reinterpret_cast<ushort4*>(&v0);
      dst[1] = *(reinterpret_cast<ushort4*>(&v0)+1);
      dst[2] = *reinterpret_cast<ushort4*>(&v1);
      dst[3] = *(reinterpret_cast<ushort4*>(&v1)+1);
    }
    __syncthreads();
    // ---- chunk softmax (redundant per-thread over own h2, no extra sync) ----
    float m_c = -INFINITY;
    for (int j=0;j<cnt;j++) m_c = fmaxf(m_c, lgs[h2][j]);
    float m_new = fmaxf(m_run, m_c);
    float c = __expf(m_run - m_new);     // first chunk: exp(-inf)=0
    m_run = m_new;
    if (d < cnt) ws[h2][d] = __expf(lgs[h2][d] - m_new);
    __syncthreads();
    // ---- pass 2: aggregate ----
    float s_c = 0.f, a_c = 0.f;
    for (int j=0;j<cnt;j++){
      float w = ws[h2][j];
      s_c += w;
      a_c = fmaf(w, (float)xls[j][h2*16 + d], a_c);
    }
    s_run = s_run*c + s_c;
    acc   = acc*c + a_c;
    __syncthreads();   // guard LDS overwrite next chunk
  }
  float o = acc/(s_run + 1e-16f) + b1[tid];
  out1[(size_t)i*128 + tid] = (__bf16)(o > 0.f ? o : expm1f(o));
}

// ---------------- layer 2 fused: chunked two-pass + log_softmax --------------
// block = dst node, 1 wave. Pass1: lane = edge (full 64-dim dot locally).
// Pass2: lane = output dim.
__global__ __launch_bounds__(64) void k_fused2(
    const int* __restrict__ off, const int* __restrict__ adj,
    const int* __restrict__ esrc, int E,
    const __bf16* __restrict__ H2, const float* __restrict__ att2,
    const float* __restrict__ b2, float* __restrict__ out)
{
  __shared__ __bf16 xls[64][68];   // stride 68: free reads in pass2
  __shared__ float  ws[64];
  __shared__ float  xr_s[64], aw_s[64];
  int i = blockIdx.x, lane = threadIdx.x;
  int begin = off[i], deg = off[i+1] - begin;
  xr_s[lane] = (float)H2[(size_t)i*128 + 64 + lane];
  aw_s[lane] = att2[lane];
  __syncthreads();

  float m_run = -INFINITY, s_run = 0.f, acc = 0.f;
  int nch = (deg + 63) >> 6;
  for (int ch=0; ch<nch; ch++){
    int base = ch*64;
    int cnt = min(64, deg - base);
    float lg = -INFINITY;
    if (lane < cnt){
      int e = adj[begin + base + lane];
      int s = (e < E) ? esrc[e] : (e - E);
      const __bf16* row = H2 + (size_t)s*128;
      float accl = 0.f;
      #pragma unroll
      for (int q=0;q<8;q++){
        bf16x8 v = *reinterpret_cast<const bf16x8*>(row + q*8);
        reinterpret_cast<ushort4*>(&xls[lane][0])[2*q]   = *reinterpret_cast<ushort4*>(&v);
        reinterpret_cast<ushort4*>(&xls[lane][0])[2*q+1] = *(reinterpret_cast<ushort4*>(&v)+1);
        #pragma unroll
        for (int j=0;j<8;j++)
          accl = fmaf(aw_s[q*8+j], lrelu((float)v[j] + xr_s[q*8+j]), accl);
      }
      lg = accl;
    }
    // chunk softmax across lanes
    float m_c = lg;
    #pragma unroll
    for (int mm=1;mm<64;mm<<=1) m_c = fmaxf(m_c, __shfl_xor(m_c, mm, 64));
    float m_new = fmaxf(m_run, m_c);
    float c = __expf(m_run - m_new);
    float w = (lane < cnt) ? __expf(lg - m_new) : 0.f;
    float s_c = w;
    #pragma unroll
    for (int mm=1;mm<64;mm<<=1) s_c += __shfl_xor(s_c, mm, 64);
    ws[lane] = w;
    m_run = m_new;
    __syncthreads();
    float a_c = 0.f;
    for (int j=0;j<cnt;j++)
      a_c = fmaf(ws[j], (float)xls[j][lane], a_c);
    s_run = s_run*c + s_c;
    acc   = acc*c + a_c;
    __syncthreads();
  }
  float o = acc/(s_run + 1e-16f) + b2[lane];
  float mx = o;
  #pragma unroll
  for (int mm=1;mm<64;mm<<=1) mx = fmaxf(mx, __shfl_xor(mx,mm,64));
  float se = __expf(o - mx);
  #pragma unroll
  for (int mm=1;mm<64;mm<<=1) se += __shfl_xor(se,mm,64);
  out[(size_t)i*64 + lane] = o - mx - __logf(se);
}

extern "C" void kernel_launch(void* const* d_in, const int* in_sizes, int n_in,
                              void* d_out, int out_size, void* d_ws, size_t ws_size,
                              hipStream_t stream)
{
  const float* x    = (const float*)d_in[0];
  const int*   ei   = (const int*)  d_in[1];
  const float* Wl1  = (const float*)d_in[2];
  const float* Wr1  = (const float*)d_in[3];
  const float* att1 = (const float*)d_in[4];
  const float* b1   = (const float*)d_in[5];
  const float* Wl2  = (const float*)d_in[6];
  const float* Wr2  = (const float*)d_in[7];
  const float* att2 = (const float*)d_in[8];
  const float* b2   = (const float*)d_in[9];
  float* out = (float*)d_out;

  const int DIN = 512;
  int N  = in_sizes[0] / DIN;     // 50000
  int E  = in_sizes[1] / 2;       // 800000
  int ET = E + N;                 // + self loops
  const int* esrc = ei;
  const int* edst = ei + E;

  char* p = (char*)d_ws;
  auto walloc = [&](size_t bytes)->void*{
    void* r = (void*)p; p += (bytes + 255) & ~(size_t)255; return r;
  };
  __bf16* xb   = (__bf16*)walloc((size_t)N*DIN*2);
  __bf16* Wt1  = (__bf16*)walloc((size_t)256*512*2);
  __bf16* Wt2  = (__bf16*)walloc((size_t)128*128*2);
  __bf16* H1   = (__bf16*)walloc((size_t)N*256*2);  // [xl1 | xr1]
  __bf16* out1 = (__bf16*)walloc((size_t)N*128*2);
  __bf16* H2   = (__bf16*)walloc((size_t)N*128*2);  // [xl2 | xr2]
  int* off    = (int*)walloc((size_t)(N+1)*4);
  int* cursor = (int*)walloc((size_t)N*4);
  int* adj    = (int*)walloc((size_t)ET*4);

  // CSR build
  hipMemsetAsync(off, 0, (size_t)(N+1)*4, stream);
  k_count_deg<<<CDIV(ET,256),256,0,stream>>>(edst, E, ET, off);
  k_scan<<<1,256,0,stream>>>(off, cursor, N);
  k_fill<<<CDIV(ET,256),256,0,stream>>>(edst, E, ET, cursor, adj);

  // prep
  int n4 = N*DIN/4;
  k_cvt_bf16<<<CDIV(n4,256),256,0,stream>>>(x, xb, n4);
  k_prep_wt<<<256,512,0,stream>>>(Wl1, Wr1, Wt1, 512, 128);
  k_prep_wt<<<128,128,0,stream>>>(Wl2, Wr2, Wt2, 128, 64);

  // Layer 1
  gemm_bf16<16><<<CDIV(N,64),256,0,stream>>>(xb, N, 512, Wt1, H1);
  k_fused1<<<N,128,0,stream>>>(off, adj, esrc, E, H1, att1, b1, out1);

  // Layer 2
  gemm_bf16<8><<<CDIV(N,64),256,0,stream>>>(out1, N, 128, Wt2, H2);
  k_fused2<<<N,64,0,stream>>>(off, adj, esrc, E, H2, att2, b2, out);
}

// Round 4
// 603.088 us; speedup vs baseline: 1.6221x; 1.2093x over previous
//
#include <hip/hip_runtime.h>
#include <math.h>

#define CDIV(a,b) (((a)+(b)-1)/(b))

typedef __bf16 bf16x8 __attribute__((ext_vector_type(8)));
typedef float  f32x4  __attribute__((ext_vector_type(4)));
typedef __attribute__((address_space(3))) uint32_t lds_u32_t;
typedef __attribute__((address_space(1))) uint32_t glb_u32_t;

__device__ __forceinline__ float lrelu(float v){ return v > 0.f ? v : 0.2f*v; }

// ---------------- CSR build (by dst) ----------------
__global__ void k_count_deg(const int* __restrict__ edst, int E, int ET, int* __restrict__ off){
  int e = blockIdx.x*blockDim.x + threadIdx.x;
  if (e >= ET) return;
  int d = (e < E) ? edst[e] : (e - E);   // self-loops appended at the end
  atomicAdd(&off[d+1], 1);
}

__global__ void k_scan(int* __restrict__ off, int* __restrict__ cursor, int n){
  __shared__ int sums[256];
  int t = threadIdx.x;
  int chunk = CDIV(n,256);
  int beg = 1 + t*chunk;
  int end = min(1 + (t+1)*chunk, n+1);
  int s = 0;
  for (int i=beg;i<end;i++) s += off[i];
  sums[t] = s;
  __syncthreads();
  if (t==0){ int a=0; for (int j=0;j<256;j++){ int v=sums[j]; sums[j]=a; a+=v; } }
  __syncthreads();
  int run = sums[t];
  if (t==0) cursor[0] = 0;
  for (int i=beg;i<end;i++){ run += off[i]; off[i] = run; if (i < n) cursor[i] = run; }
}

__global__ void k_fill(const int* __restrict__ edst, int E, int ET,
                       int* __restrict__ cursor, int* __restrict__ adj){
  int e = blockIdx.x*blockDim.x + threadIdx.x;
  if (e >= ET) return;
  int d = (e < E) ? edst[e] : (e - E);
  int pos = atomicAdd(&cursor[d], 1);
  adj[pos] = e;
}

// ---------------- prep: fp32 -> bf16 convert ----------------
__global__ void k_cvt_bf16(const float* __restrict__ in, __bf16* __restrict__ out, int n4){
  int i = blockIdx.x*blockDim.x + threadIdx.x;
  if (i >= n4) return;
  float4 v = reinterpret_cast<const float4*>(in)[i];
  __bf16 o[4] = {(__bf16)v.x,(__bf16)v.y,(__bf16)v.z,(__bf16)v.w};
  *reinterpret_cast<ushort4*>(out + (size_t)i*4) =
      *reinterpret_cast<ushort4*>(o);
}

// ---------------- prep: Wt[c][k] = concat(Wl,Wr)[k][c] as bf16 ----------------
__global__ void k_prep_wt(const float* __restrict__ Wl, const float* __restrict__ Wr,
                          __bf16* __restrict__ Wt, int K, int Nh){
  int c = blockIdx.x, k = threadIdx.x;
  float v = (c < Nh) ? Wl[(size_t)k*Nh + c] : Wr[(size_t)k*Nh + (c - Nh)];
  Wt[(size_t)c*K + k] = (__bf16)v;
}

// ---------------- bf16 MFMA GEMM, m97-style ----------------
// C[M,N] = A[M,K] @ Bt[N,K]^T. 128x128 tile, BK=32, 4 waves (2x2 of 64x64),
// global_load_lds(16B) staging, double-buffered LDS, XOR-swizzled slots.
__global__ __launch_bounds__(256) void gemm_mfma(
    const __bf16* __restrict__ A, int M, int K,
    const __bf16* __restrict__ Bt, int N,
    __bf16* __restrict__ C)
{
  __shared__ __bf16 As[2][128*32];
  __shared__ __bf16 Bs[2][128*32];
  int tid = threadIdx.x;
  int w = tid >> 6, lane = tid & 63;
  int g = lane >> 4, r16 = lane & 15;
  int wr = w >> 1, wc = w & 1;
  int row0 = blockIdx.x * 128;
  int col0 = blockIdx.y * 128;
  int srow = tid >> 2, sslot = tid & 3;   // staging: row within tile, 16B slot

  auto f = [](int r){ return (r + (r >> 2)) & 3; };   // slot swizzle

  f32x4 acc[4][4];
  #pragma unroll
  for (int m=0;m<4;m++)
    #pragma unroll
    for (int n=0;n<4;n++) acc[m][n] = (f32x4){0.f,0.f,0.f,0.f};

  auto STAGE = [&](int buf, int kt){
    #pragma unroll
    for (int i=0;i<2;i++){
      int trow = i*64 + srow;
      int arow = row0 + trow; if (arow >= M) arow = M-1;
      const __bf16* ga = A + (size_t)arow*K + kt*32 + ((sslot ^ f(trow))<<3);
      __builtin_amdgcn_global_load_lds((const glb_u32_t*)(const void*)ga,
          (lds_u32_t*)(void*)&As[buf][(i*64 + w*16)*32], 16, 0, 0);
      const __bf16* gb = Bt + (size_t)(col0 + trow)*K + kt*32 + ((sslot ^ f(trow))<<3);
      __builtin_amdgcn_global_load_lds((const glb_u32_t*)(const void*)gb,
          (lds_u32_t*)(void*)&Bs[buf][(i*64 + w*16)*32], 16, 0, 0);
    }
  };

  int nk = K >> 5;
  STAGE(0, 0);
  for (int kt = 0; kt < nk; ++kt){
    int cur = kt & 1;
    __syncthreads();                       // drains staged loads (vmcnt0) + guards reuse
    if (kt+1 < nk) STAGE(cur^1, kt+1);     // prefetch overlaps compute below
    bf16x8 a[4], b[4];
    #pragma unroll
    for (int m=0;m<4;m++){
      int row = wr*64 + m*16 + r16;
      a[m] = *reinterpret_cast<const bf16x8*>(&As[cur][row*32 + ((g ^ f(row))<<3)]);
    }
    #pragma unroll
    for (int n=0;n<4;n++){
      int row = wc*64 + n*16 + r16;
      b[n] = *reinterpret_cast<const bf16x8*>(&Bs[cur][row*32 + ((g ^ f(row))<<3)]);
    }
    #pragma unroll
    for (int m=0;m<4;m++)
      #pragma unroll
      for (int n=0;n<4;n++)
        acc[m][n] = __builtin_amdgcn_mfma_f32_16x16x32_bf16(a[m], b[n], acc[m][n], 0, 0, 0);
  }

  #pragma unroll
  for (int m=0;m<4;m++){
    int row_c = row0 + wr*64 + m*16 + g*4;
    #pragma unroll
    for (int n=0;n<4;n++){
      int col_c = col0 + wc*64 + n*16 + r16;
      #pragma unroll
      for (int r=0;r<4;r++)
        if (row_c + r < M) C[(size_t)(row_c+r)*N + col_c] = (__bf16)acc[m][n][r];
    }
  }
}

// ---------------- layer 1 fused: chunked two-pass softmax + aggregate + elu ---
__global__ __launch_bounds__(128) void k_fused1(
    const int* __restrict__ off, const int* __restrict__ adj,
    const int* __restrict__ esrc, int E,
    const __bf16* __restrict__ H1, const float* __restrict__ att1,
    const float* __restrict__ b1, __bf16* __restrict__ out1)
{
  __shared__ __bf16 xls[16][132];   // stride 132: free reads in pass2
  __shared__ float  lgs[8][17];
  __shared__ float  ws [8][17];
  int i = blockIdx.x;
  int tid = threadIdx.x;
  int e_id = tid >> 3, h1 = tid & 7;
  int h2 = tid >> 4, d  = tid & 15;
  int begin = off[i], deg = off[i+1] - begin;

  float xr1[16], aw1[16];
  #pragma unroll
  for (int j=0;j<16;j++){
    xr1[j] = (float)H1[(size_t)i*256 + 128 + h1*16 + j];
    aw1[j] = att1[h1*16 + j];
  }

  float m_run = -INFINITY, s_run = 0.f, acc = 0.f;
  int nch = (deg + 15) >> 4;
  for (int ch=0; ch<nch; ch++){
    int base = ch*16;
    int cnt = min(16, deg - base);
    int k = base + e_id;
    if (e_id < cnt){
      int e = adj[begin + k];
      int s = (e < E) ? esrc[e] : (e - E);
      const __bf16* row = H1 + (size_t)s*256 + h1*16;
      bf16x8 v0 = *reinterpret_cast<const bf16x8*>(row);
      bf16x8 v1 = *reinterpret_cast<const bf16x8*>(row + 8);
      float lg = 0.f;
      #pragma unroll
      for (int j=0;j<8;j++){
        lg = fmaf(aw1[j],   lrelu((float)v0[j] + xr1[j]),   lg);
        lg = fmaf(aw1[j+8], lrelu((float)v1[j] + xr1[j+8]), lg);
      }
      lgs[h1][e_id] = lg;
      ushort4* dst = reinterpret_cast<ushort4*>(&xls[e_id][h1*16]);
      dst[0] = *reinterpret_cast<ushort4*>(&v0);
      dst[1] = *(reinterpret_cast<ushort4*>(&v0)+1);
      dst[2] = *reinterpret_cast<ushort4*>(&v1);
      dst[3] = *(reinterpret_cast<ushort4*>(&v1)+1);
    }
    __syncthreads();
    float m_c = -INFINITY;
    for (int j=0;j<cnt;j++) m_c = fmaxf(m_c, lgs[h2][j]);
    float m_new = fmaxf(m_run, m_c);
    float c = __expf(m_run - m_new);
    m_run = m_new;
    if (d < cnt) ws[h2][d] = __expf(lgs[h2][d] - m_new);
    __syncthreads();
    float s_c = 0.f, a_c = 0.f;
    for (int j=0;j<cnt;j++){
      float w = ws[h2][j];
      s_c += w;
      a_c = fmaf(w, (float)xls[j][h2*16 + d], a_c);
    }
    s_run = s_run*c + s_c;
    acc   = acc*c + a_c;
    __syncthreads();
  }
  float o = acc/(s_run + 1e-16f) + b1[tid];
  out1[(size_t)i*128 + tid] = (__bf16)(o > 0.f ? o : expm1f(o));
}

// ---------------- layer 2 fused: chunked two-pass + log_softmax --------------
__global__ __launch_bounds__(64) void k_fused2(
    const int* __restrict__ off, const int* __restrict__ adj,
    const int* __restrict__ esrc, int E,
    const __bf16* __restrict__ H2, const float* __restrict__ att2,
    const float* __restrict__ b2, float* __restrict__ out)
{
  __shared__ __bf16 xls[64][68];   // stride 68: free reads in pass2
  __shared__ float  ws[64];
  __shared__ float  xr_s[64], aw_s[64];
  int i = blockIdx.x, lane = threadIdx.x;
  int begin = off[i], deg = off[i+1] - begin;
  xr_s[lane] = (float)H2[(size_t)i*128 + 64 + lane];
  aw_s[lane] = att2[lane];
  __syncthreads();

  float m_run = -INFINITY, s_run = 0.f, acc = 0.f;
  int nch = (deg + 63) >> 6;
  for (int ch=0; ch<nch; ch++){
    int base = ch*64;
    int cnt = min(64, deg - base);
    float lg = -INFINITY;
    if (lane < cnt){
      int e = adj[begin + base + lane];
      int s = (e < E) ? esrc[e] : (e - E);
      const __bf16* row = H2 + (size_t)s*128;
      float accl = 0.f;
      #pragma unroll
      for (int q=0;q<8;q++){
        bf16x8 v = *reinterpret_cast<const bf16x8*>(row + q*8);
        reinterpret_cast<ushort4*>(&xls[lane][0])[2*q]   = *reinterpret_cast<ushort4*>(&v);
        reinterpret_cast<ushort4*>(&xls[lane][0])[2*q+1] = *(reinterpret_cast<ushort4*>(&v)+1);
        #pragma unroll
        for (int j=0;j<8;j++)
          accl = fmaf(aw_s[q*8+j], lrelu((float)v[j] + xr_s[q*8+j]), accl);
      }
      lg = accl;
    }
    float m_c = lg;
    #pragma unroll
    for (int mm=1;mm<64;mm<<=1) m_c = fmaxf(m_c, __shfl_xor(m_c, mm, 64));
    float m_new = fmaxf(m_run, m_c);
    float c = __expf(m_run - m_new);
    float w = (lane < cnt) ? __expf(lg - m_new) : 0.f;
    float s_c = w;
    #pragma unroll
    for (int mm=1;mm<64;mm<<=1) s_c += __shfl_xor(s_c, mm, 64);
    ws[lane] = w;
    m_run = m_new;
    __syncthreads();
    float a_c = 0.f;
    for (int j=0;j<cnt;j++)
      a_c = fmaf(ws[j], (float)xls[j][lane], a_c);
    s_run = s_run*c + s_c;
    acc   = acc*c + a_c;
    __syncthreads();
  }
  float o = acc/(s_run + 1e-16f) + b2[lane];
  float mx = o;
  #pragma unroll
  for (int mm=1;mm<64;mm<<=1) mx = fmaxf(mx, __shfl_xor(mx,mm,64));
  float se = __expf(o - mx);
  #pragma unroll
  for (int mm=1;mm<64;mm<<=1) se += __shfl_xor(se,mm,64);
  out[(size_t)i*64 + lane] = o - mx - __logf(se);
}

extern "C" void kernel_launch(void* const* d_in, const int* in_sizes, int n_in,
                              void* d_out, int out_size, void* d_ws, size_t ws_size,
                              hipStream_t stream)
{
  const float* x    = (const float*)d_in[0];
  const int*   ei   = (const int*)  d_in[1];
  const float* Wl1  = (const float*)d_in[2];
  const float* Wr1  = (const float*)d_in[3];
  const float* att1 = (const float*)d_in[4];
  const float* b1   = (const float*)d_in[5];
  const float* Wl2  = (const float*)d_in[6];
  const float* Wr2  = (const float*)d_in[7];
  const float* att2 = (const float*)d_in[8];
  const float* b2   = (const float*)d_in[9];
  float* out = (float*)d_out;

  const int DIN = 512;
  int N  = in_sizes[0] / DIN;     // 50000
  int E  = in_sizes[1] / 2;       // 800000
  int ET = E + N;                 // + self loops
  const int* esrc = ei;
  const int* edst = ei + E;

  char* p = (char*)d_ws;
  auto walloc = [&](size_t bytes)->void*{
    void* r = (void*)p; p += (bytes + 255) & ~(size_t)255; return r;
  };
  __bf16* xb   = (__bf16*)walloc((size_t)N*DIN*2);
  __bf16* Wt1  = (__bf16*)walloc((size_t)256*512*2);
  __bf16* Wt2  = (__bf16*)walloc((size_t)128*128*2);
  __bf16* H1   = (__bf16*)walloc((size_t)N*256*2);  // [xl1 | xr1]
  __bf16* out1 = (__bf16*)walloc((size_t)N*128*2);
  __bf16* H2   = (__bf16*)walloc((size_t)N*128*2);  // [xl2 | xr2]
  int* off    = (int*)walloc((size_t)(N+1)*4);
  int* cursor = (int*)walloc((size_t)N*4);
  int* adj    = (int*)walloc((size_t)ET*4);

  // CSR build
  hipMemsetAsync(off, 0, (size_t)(N+1)*4, stream);
  k_count_deg<<<CDIV(ET,256),256,0,stream>>>(edst, E, ET, off);
  k_scan<<<1,256,0,stream>>>(off, cursor, N);
  k_fill<<<CDIV(ET,256),256,0,stream>>>(edst, E, ET, cursor, adj);

  // prep
  int n4 = N*DIN/4;
  k_cvt_bf16<<<CDIV(n4,256),256,0,stream>>>(x, xb, n4);
  k_prep_wt<<<256,512,0,stream>>>(Wl1, Wr1, Wt1, 512, 128);
  k_prep_wt<<<128,128,0,stream>>>(Wl2, Wr2, Wt2, 128, 64);

  // Layer 1: H1[N,256] = xb[N,512] @ Wt1[256,512]^T
  dim3 g1(CDIV(N,128), 2);
  gemm_mfma<<<g1,256,0,stream>>>(xb, N, 512, Wt1, 256, H1);
  k_fused1<<<N,128,0,stream>>>(off, adj, esrc, E, H1, att1, b1, out1);

  // Layer 2: H2[N,128] = out1[N,128] @ Wt2[128,128]^T
  dim3 g2(CDIV(N,128), 1);
  gemm_mfma<<<g2,256,0,stream>>>(out1, N, 128, Wt2, 128, H2);
  k_fused2<<<N,64,0,stream>>>(off, adj, esrc, E, H2, att2, b2, out);
}

// Round 5
// 487.453 us; speedup vs baseline: 2.0069x; 1.2372x over previous
//
#include <hip/hip_runtime.h>
#include <math.h>

#define CDIV(a,b) (((a)+(b)-1)/(b))

typedef __bf16 bf16x8 __attribute__((ext_vector_type(8)));
typedef float  f32x4  __attribute__((ext_vector_type(4)));
typedef __attribute__((address_space(3))) uint32_t lds_u32_t;
typedef __attribute__((address_space(1))) uint32_t glb_u32_t;

__device__ __forceinline__ float lrelu(float v){ return v > 0.f ? v : 0.2f*v; }

// ---------------- CSR build (by dst) ----------------
__global__ void k_count_deg(const int* __restrict__ edst, int E, int ET, int* __restrict__ off){
  int e = blockIdx.x*blockDim.x + threadIdx.x;
  if (e >= ET) return;
  int d = (e < E) ? edst[e] : (e - E);   // self-loops appended at the end
  atomicAdd(&off[d+1], 1);
}

// hierarchical scan, step A: per-block inclusive scan (in place) + block totals
__global__ __launch_bounds__(256) void k_scan_a(int* __restrict__ cnt, int n, int* __restrict__ bsum){
  int i = blockIdx.x*256 + threadIdx.x;
  int lane = threadIdx.x & 63, wv = threadIdx.x >> 6;
  int x = (i < n) ? cnt[i] : 0;
  #pragma unroll
  for (int d=1; d<64; d<<=1){ int y = __shfl_up(x, d, 64); if (lane >= d) x += y; }
  __shared__ int wsum[4];
  if (lane == 63) wsum[wv] = x;
  __syncthreads();
  #pragma unroll
  for (int j=0;j<3;j++) if (wv > j) x += wsum[j];
  if (i < n) cnt[i] = x;
  if (threadIdx.x == 255) bsum[blockIdx.x] = x;
}

// step B: exclusive scan of block totals (nb <= 256)
__global__ __launch_bounds__(256) void k_scan_b(int* __restrict__ bsum, int nb){
  int t = threadIdx.x;
  int lane = t & 63, wv = t >> 6;
  int v = (t < nb) ? bsum[t] : 0;
  int x = v;
  #pragma unroll
  for (int d=1; d<64; d<<=1){ int y = __shfl_up(x, d, 64); if (lane >= d) x += y; }
  __shared__ int wsum[4];
  if (lane == 63) wsum[wv] = x;
  __syncthreads();
  #pragma unroll
  for (int j=0;j<3;j++) if (wv > j) x += wsum[j];
  if (t < nb) bsum[t] = x - v;   // exclusive
}

// step C: add block prefix; produce final off[] (at cnt-1) and cursor[]
__global__ __launch_bounds__(256) void k_scan_c(int* __restrict__ off, int* __restrict__ cursor,
                                                const int* __restrict__ bsum, int n){
  int i = blockIdx.x*256 + threadIdx.x;   // element 0..n-1 maps to off[1+i]
  if (i >= n) return;
  int v = off[1+i] + bsum[blockIdx.x];
  off[1+i] = v;
  if (i+1 < n) cursor[i+1] = v;
  if (i == 0) cursor[0] = 0;
}

__global__ void k_fill(const int* __restrict__ edst, int E, int ET,
                       int* __restrict__ cursor, int* __restrict__ adj){
  int e = blockIdx.x*blockDim.x + threadIdx.x;
  if (e >= ET) return;
  int d = (e < E) ? edst[e] : (e - E);
  int pos = atomicAdd(&cursor[d], 1);
  adj[pos] = e;
}

// ---------------- prep: fp32 -> bf16 convert ----------------
__global__ void k_cvt_bf16(const float* __restrict__ in, __bf16* __restrict__ out, int n4){
  int i = blockIdx.x*blockDim.x + threadIdx.x;
  if (i >= n4) return;
  float4 v = reinterpret_cast<const float4*>(in)[i];
  __bf16 o[4] = {(__bf16)v.x,(__bf16)v.y,(__bf16)v.z,(__bf16)v.w};
  *reinterpret_cast<ushort4*>(out + (size_t)i*4) =
      *reinterpret_cast<ushort4*>(o);
}

// ---------------- prep: Wt[c][k] = concat(Wl,Wr)[k][c] as bf16 ----------------
__global__ void k_prep_wt(const float* __restrict__ Wl, const float* __restrict__ Wr,
                          __bf16* __restrict__ Wt, int K, int Nh){
  int c = blockIdx.x, k = threadIdx.x;
  float v = (c < Nh) ? Wl[(size_t)k*Nh + c] : Wr[(size_t)k*Nh + (c - Nh)];
  Wt[(size_t)c*K + k] = (__bf16)v;
}

// ---------------- bf16 MFMA GEMM, m97-style ----------------
__global__ __launch_bounds__(256) void gemm_mfma(
    const __bf16* __restrict__ A, int M, int K,
    const __bf16* __restrict__ Bt, int N,
    __bf16* __restrict__ C)
{
  __shared__ __bf16 As[2][128*32];
  __shared__ __bf16 Bs[2][128*32];
  int tid = threadIdx.x;
  int w = tid >> 6, lane = tid & 63;
  int g = lane >> 4, r16 = lane & 15;
  int wr = w >> 1, wc = w & 1;
  int row0 = blockIdx.x * 128;
  int col0 = blockIdx.y * 128;
  int srow = tid >> 2, sslot = tid & 3;

  auto f = [](int r){ return (r + (r >> 2)) & 3; };

  f32x4 acc[4][4];
  #pragma unroll
  for (int m=0;m<4;m++)
    #pragma unroll
    for (int n=0;n<4;n++) acc[m][n] = (f32x4){0.f,0.f,0.f,0.f};

  auto STAGE = [&](int buf, int kt){
    #pragma unroll
    for (int i=0;i<2;i++){
      int trow = i*64 + srow;
      int arow = row0 + trow; if (arow >= M) arow = M-1;
      const __bf16* ga = A + (size_t)arow*K + kt*32 + ((sslot ^ f(trow))<<3);
      __builtin_amdgcn_global_load_lds((const glb_u32_t*)(const void*)ga,
          (lds_u32_t*)(void*)&As[buf][(i*64 + w*16)*32], 16, 0, 0);
      const __bf16* gb = Bt + (size_t)(col0 + trow)*K + kt*32 + ((sslot ^ f(trow))<<3);
      __builtin_amdgcn_global_load_lds((const glb_u32_t*)(const void*)gb,
          (lds_u32_t*)(void*)&Bs[buf][(i*64 + w*16)*32], 16, 0, 0);
    }
  };

  int nk = K >> 5;
  STAGE(0, 0);
  for (int kt = 0; kt < nk; ++kt){
    int cur = kt & 1;
    __syncthreads();
    if (kt+1 < nk) STAGE(cur^1, kt+1);
    bf16x8 a[4], b[4];
    #pragma unroll
    for (int m=0;m<4;m++){
      int row = wr*64 + m*16 + r16;
      a[m] = *reinterpret_cast<const bf16x8*>(&As[cur][row*32 + ((g ^ f(row))<<3)]);
    }
    #pragma unroll
    for (int n=0;n<4;n++){
      int row = wc*64 + n*16 + r16;
      b[n] = *reinterpret_cast<const bf16x8*>(&Bs[cur][row*32 + ((g ^ f(row))<<3)]);
    }
    #pragma unroll
    for (int m=0;m<4;m++)
      #pragma unroll
      for (int n=0;n<4;n++)
        acc[m][n] = __builtin_amdgcn_mfma_f32_16x16x32_bf16(a[m], b[n], acc[m][n], 0, 0, 0);
  }

  #pragma unroll
  for (int m=0;m<4;m++){
    int row_c = row0 + wr*64 + m*16 + g*4;
    #pragma unroll
    for (int n=0;n<4;n++){
      int col_c = col0 + wc*64 + n*16 + r16;
      #pragma unroll
      for (int r=0;r<4;r++)
        if (row_c + r < M) C[(size_t)(row_c+r)*N + col_c] = (__bf16)acc[m][n][r];
    }
  }
}

// ---------------- layer 1 fused: chunked two-pass softmax + aggregate + elu ---
__global__ __launch_bounds__(128) void k_fused1(
    const int* __restrict__ off, const int* __restrict__ adj,
    const int* __restrict__ esrc, int E,
    const __bf16* __restrict__ H1, const float* __restrict__ att1,
    const float* __restrict__ b1, __bf16* __restrict__ out1)
{
  __shared__ __bf16 xls[16][132];
  __shared__ float  lgs[8][17];
  __shared__ float  ws [8][17];
  int i = blockIdx.x;
  int tid = threadIdx.x;
  int e_id = tid >> 3, h1 = tid & 7;
  int h2 = tid >> 4, d  = tid & 15;
  int begin = off[i], deg = off[i+1] - begin;

  float xr1[16], aw1[16];
  #pragma unroll
  for (int j=0;j<16;j++){
    xr1[j] = (float)H1[(size_t)i*256 + 128 + h1*16 + j];
    aw1[j] = att1[h1*16 + j];
  }

  float m_run = -INFINITY, s_run = 0.f, acc = 0.f;
  int nch = (deg + 15) >> 4;
  for (int ch=0; ch<nch; ch++){
    int base = ch*16;
    int cnt = min(16, deg - base);
    int k = base + e_id;
    if (e_id < cnt){
      int e = adj[begin + k];
      int s = (e < E) ? esrc[e] : (e - E);
      const __bf16* row = H1 + (size_t)s*256 + h1*16;
      bf16x8 v0 = *reinterpret_cast<const bf16x8*>(row);
      bf16x8 v1 = *reinterpret_cast<const bf16x8*>(row + 8);
      float lg = 0.f;
      #pragma unroll
      for (int j=0;j<8;j++){
        lg = fmaf(aw1[j],   lrelu((float)v0[j] + xr1[j]),   lg);
        lg = fmaf(aw1[j+8], lrelu((float)v1[j] + xr1[j+8]), lg);
      }
      lgs[h1][e_id] = lg;
      ushort4* dst = reinterpret_cast<ushort4*>(&xls[e_id][h1*16]);
      dst[0] = *reinterpret_cast<ushort4*>(&v0);
      dst[1] = *(reinterpret_cast<ushort4*>(&v0)+1);
      dst[2] = *reinterpret_cast<ushort4*>(&v1);
      dst[3] = *(reinterpret_cast<ushort4*>(&v1)+1);
    }
    __syncthreads();
    float m_c = -INFINITY;
    for (int j=0;j<cnt;j++) m_c = fmaxf(m_c, lgs[h2][j]);
    float m_new = fmaxf(m_run, m_c);
    float c = __expf(m_run - m_new);
    m_run = m_new;
    if (d < cnt) ws[h2][d] = __expf(lgs[h2][d] - m_new);
    __syncthreads();
    float s_c = 0.f, a_c = 0.f;
    for (int j=0;j<cnt;j++){
      float w = ws[h2][j];
      s_c += w;
      a_c = fmaf(w, (float)xls[j][h2*16 + d], a_c);
    }
    s_run = s_run*c + s_c;
    acc   = acc*c + a_c;
    __syncthreads();
  }
  float o = acc/(s_run + 1e-16f) + b1[tid];
  out1[(size_t)i*128 + tid] = (__bf16)(o > 0.f ? o : expm1f(o));
}

// ---------------- layer 2 fused: chunked two-pass + log_softmax --------------
__global__ __launch_bounds__(64) void k_fused2(
    const int* __restrict__ off, const int* __restrict__ adj,
    const int* __restrict__ esrc, int E,
    const __bf16* __restrict__ H2, const float* __restrict__ att2,
    const float* __restrict__ b2, float* __restrict__ out)
{
  __shared__ __bf16 xls[64][68];
  __shared__ float  ws[64];
  __shared__ float  xr_s[64], aw_s[64];
  int i = blockIdx.x, lane = threadIdx.x;
  int begin = off[i], deg = off[i+1] - begin;
  xr_s[lane] = (float)H2[(size_t)i*128 + 64 + lane];
  aw_s[lane] = att2[lane];
  __syncthreads();

  float m_run = -INFINITY, s_run = 0.f, acc = 0.f;
  int nch = (deg + 63) >> 6;
  for (int ch=0; ch<nch; ch++){
    int base = ch*64;
    int cnt = min(64, deg - base);
    float lg = -INFINITY;
    if (lane < cnt){
      int e = adj[begin + base + lane];
      int s = (e < E) ? esrc[e] : (e - E);
      const __bf16* row = H2 + (size_t)s*128;
      float accl = 0.f;
      #pragma unroll
      for (int q=0;q<8;q++){
        bf16x8 v = *reinterpret_cast<const bf16x8*>(row + q*8);
        reinterpret_cast<ushort4*>(&xls[lane][0])[2*q]   = *reinterpret_cast<ushort4*>(&v);
        reinterpret_cast<ushort4*>(&xls[lane][0])[2*q+1] = *(reinterpret_cast<ushort4*>(&v)+1);
        #pragma unroll
        for (int j=0;j<8;j++)
          accl = fmaf(aw_s[q*8+j], lrelu((float)v[j] + xr_s[q*8+j]), accl);
      }
      lg = accl;
    }
    float m_c = lg;
    #pragma unroll
    for (int mm=1;mm<64;mm<<=1) m_c = fmaxf(m_c, __shfl_xor(m_c, mm, 64));
    float m_new = fmaxf(m_run, m_c);
    float c = __expf(m_run - m_new);
    float w = (lane < cnt) ? __expf(lg - m_new) : 0.f;
    float s_c = w;
    #pragma unroll
    for (int mm=1;mm<64;mm<<=1) s_c += __shfl_xor(s_c, mm, 64);
    ws[lane] = w;
    m_run = m_new;
    __syncthreads();
    float a_c = 0.f;
    for (int j=0;j<cnt;j++)
      a_c = fmaf(ws[j], (float)xls[j][lane], a_c);
    s_run = s_run*c + s_c;
    acc   = acc*c + a_c;
    __syncthreads();
  }
  float o = acc/(s_run + 1e-16f) + b2[lane];
  float mx = o;
  #pragma unroll
  for (int mm=1;mm<64;mm<<=1) mx = fmaxf(mx, __shfl_xor(mx,mm,64));
  float se = __expf(o - mx);
  #pragma unroll
  for (int mm=1;mm<64;mm<<=1) se += __shfl_xor(se,mm,64);
  out[(size_t)i*64 + lane] = o - mx - __logf(se);
}

extern "C" void kernel_launch(void* const* d_in, const int* in_sizes, int n_in,
                              void* d_out, int out_size, void* d_ws, size_t ws_size,
                              hipStream_t stream)
{
  const float* x    = (const float*)d_in[0];
  const int*   ei   = (const int*)  d_in[1];
  const float* Wl1  = (const float*)d_in[2];
  const float* Wr1  = (const float*)d_in[3];
  const float* att1 = (const float*)d_in[4];
  const float* b1   = (const float*)d_in[5];
  const float* Wl2  = (const float*)d_in[6];
  const float* Wr2  = (const float*)d_in[7];
  const float* att2 = (const float*)d_in[8];
  const float* b2   = (const float*)d_in[9];
  float* out = (float*)d_out;

  const int DIN = 512;
  int N  = in_sizes[0] / DIN;     // 50000
  int E  = in_sizes[1] / 2;       // 800000
  int ET = E + N;                 // + self loops
  const int* esrc = ei;
  const int* edst = ei + E;

  char* p = (char*)d_ws;
  auto walloc = [&](size_t bytes)->void*{
    void* r = (void*)p; p += (bytes + 255) & ~(size_t)255; return r;
  };
  __bf16* xb   = (__bf16*)walloc((size_t)N*DIN*2);
  __bf16* Wt1  = (__bf16*)walloc((size_t)256*512*2);
  __bf16* Wt2  = (__bf16*)walloc((size_t)128*128*2);
  __bf16* H1   = (__bf16*)walloc((size_t)N*256*2);  // [xl1 | xr1]
  __bf16* out1 = (__bf16*)walloc((size_t)N*128*2);
  __bf16* H2   = (__bf16*)walloc((size_t)N*128*2);  // [xl2 | xr2]
  int* off    = (int*)walloc((size_t)(N+1)*4);
  int* cursor = (int*)walloc((size_t)N*4);
  int* adj    = (int*)walloc((size_t)ET*4);
  int* bsum   = (int*)walloc((size_t)256*4);

  // CSR build (hierarchical scan: ~8 us total vs 124 us single-block)
  int NB = CDIV(N,256);
  hipMemsetAsync(off, 0, (size_t)(N+1)*4, stream);
  k_count_deg<<<CDIV(ET,256),256,0,stream>>>(edst, E, ET, off);
  k_scan_a<<<NB,256,0,stream>>>(off+1, N, bsum);
  k_scan_b<<<1,256,0,stream>>>(bsum, NB);
  k_scan_c<<<NB,256,0,stream>>>(off, cursor, bsum, N);
  k_fill<<<CDIV(ET,256),256,0,stream>>>(edst, E, ET, cursor, adj);

  // prep
  int n4 = N*DIN/4;
  k_cvt_bf16<<<CDIV(n4,256),256,0,stream>>>(x, xb, n4);
  k_prep_wt<<<256,512,0,stream>>>(Wl1, Wr1, Wt1, 512, 128);
  k_prep_wt<<<128,128,0,stream>>>(Wl2, Wr2, Wt2, 128, 64);

  // Layer 1: H1[N,256] = xb[N,512] @ Wt1[256,512]^T
  dim3 g1(CDIV(N,128), 2);
  gemm_mfma<<<g1,256,0,stream>>>(xb, N, 512, Wt1, 256, H1);
  k_fused1<<<N,128,0,stream>>>(off, adj, esrc, E, H1, att1, b1, out1);

  // Layer 2: H2[N,128] = out1[N,128] @ Wt2[128,128]^T
  dim3 g2(CDIV(N,128), 1);
  gemm_mfma<<<g2,256,0,stream>>>(out1, N, 128, Wt2, 128, H2);
  k_fused2<<<N,64,0,stream>>>(off, adj, esrc, E, H2, att2, b2, out);
}

// Round 6
// 476.415 us; speedup vs baseline: 2.0534x; 1.0232x over previous
//
#include <hip/hip_runtime.h>
#include <math.h>

#define CDIV(a,b) (((a)+(b)-1)/(b))

typedef __bf16 bf16x8 __attribute__((ext_vector_type(8)));
typedef float  f32x4  __attribute__((ext_vector_type(4)));
typedef __attribute__((address_space(3))) uint32_t lds_u32_t;
typedef __attribute__((address_space(1))) uint32_t glb_u32_t;

__device__ __forceinline__ float lrelu(float v){ return fmaxf(v, 0.2f*v); }

// ---------------- CSR build (by dst) ----------------
__global__ void k_count_deg(const int* __restrict__ edst, int E, int ET, int* __restrict__ off){
  int e = blockIdx.x*blockDim.x + threadIdx.x;
  if (e >= ET) return;
  int d = (e < E) ? edst[e] : (e - E);   // self-loops appended at the end
  atomicAdd(&off[d+1], 1);
}

__global__ __launch_bounds__(256) void k_scan_a(int* __restrict__ cnt, int n, int* __restrict__ bsum){
  int i = blockIdx.x*256 + threadIdx.x;
  int lane = threadIdx.x & 63, wv = threadIdx.x >> 6;
  int x = (i < n) ? cnt[i] : 0;
  #pragma unroll
  for (int d=1; d<64; d<<=1){ int y = __shfl_up(x, d, 64); if (lane >= d) x += y; }
  __shared__ int wsum[4];
  if (lane == 63) wsum[wv] = x;
  __syncthreads();
  #pragma unroll
  for (int j=0;j<3;j++) if (wv > j) x += wsum[j];
  if (i < n) cnt[i] = x;
  if (threadIdx.x == 255) bsum[blockIdx.x] = x;
}

__global__ __launch_bounds__(256) void k_scan_b(int* __restrict__ bsum, int nb){
  int t = threadIdx.x;
  int lane = t & 63, wv = t >> 6;
  int v = (t < nb) ? bsum[t] : 0;
  int x = v;
  #pragma unroll
  for (int d=1; d<64; d<<=1){ int y = __shfl_up(x, d, 64); if (lane >= d) x += y; }
  __shared__ int wsum[4];
  if (lane == 63) wsum[wv] = x;
  __syncthreads();
  #pragma unroll
  for (int j=0;j<3;j++) if (wv > j) x += wsum[j];
  if (t < nb) bsum[t] = x - v;   // exclusive
}

__global__ __launch_bounds__(256) void k_scan_c(int* __restrict__ off, int* __restrict__ cursor,
                                                const int* __restrict__ bsum, int n){
  int i = blockIdx.x*256 + threadIdx.x;
  if (i >= n) return;
  int v = off[1+i] + bsum[blockIdx.x];
  off[1+i] = v;
  if (i+1 < n) cursor[i+1] = v;
  if (i == 0) cursor[0] = 0;
}

__global__ void k_fill(const int* __restrict__ edst, int E, int ET,
                       int* __restrict__ cursor, int* __restrict__ adj){
  int e = blockIdx.x*blockDim.x + threadIdx.x;
  if (e >= ET) return;
  int d = (e < E) ? edst[e] : (e - E);
  int pos = atomicAdd(&cursor[d], 1);
  adj[pos] = e;
}

// ---------------- prep: fp32 -> bf16 convert ----------------
__global__ void k_cvt_bf16(const float* __restrict__ in, __bf16* __restrict__ out, int n4){
  int i = blockIdx.x*blockDim.x + threadIdx.x;
  if (i >= n4) return;
  float4 v = reinterpret_cast<const float4*>(in)[i];
  __bf16 o[4] = {(__bf16)v.x,(__bf16)v.y,(__bf16)v.z,(__bf16)v.w};
  *reinterpret_cast<ushort4*>(out + (size_t)i*4) =
      *reinterpret_cast<ushort4*>(o);
}

// ---------------- prep: Wt[c][k] = concat(Wl,Wr)[k][c] as bf16 ----------------
__global__ void k_prep_wt(const float* __restrict__ Wl, const float* __restrict__ Wr,
                          __bf16* __restrict__ Wt, int K, int Nh){
  int c = blockIdx.x, k = threadIdx.x;
  float v = (c < Nh) ? Wl[(size_t)k*Nh + c] : Wr[(size_t)k*Nh + (c - Nh)];
  Wt[(size_t)c*K + k] = (__bf16)v;
}

// ---------------- bf16 MFMA GEMM, m97-style ----------------
__global__ __launch_bounds__(256) void gemm_mfma(
    const __bf16* __restrict__ A, int M, int K,
    const __bf16* __restrict__ Bt, int N,
    __bf16* __restrict__ C)
{
  __shared__ __bf16 As[2][128*32];
  __shared__ __bf16 Bs[2][128*32];
  int tid = threadIdx.x;
  int w = tid >> 6, lane = tid & 63;
  int g = lane >> 4, r16 = lane & 15;
  int wr = w >> 1, wc = w & 1;
  int row0 = blockIdx.x * 128;
  int col0 = blockIdx.y * 128;
  int srow = tid >> 2, sslot = tid & 3;

  auto f = [](int r){ return (r + (r >> 2)) & 3; };

  f32x4 acc[4][4];
  #pragma unroll
  for (int m=0;m<4;m++)
    #pragma unroll
    for (int n=0;n<4;n++) acc[m][n] = (f32x4){0.f,0.f,0.f,0.f};

  auto STAGE = [&](int buf, int kt){
    #pragma unroll
    for (int i=0;i<2;i++){
      int trow = i*64 + srow;
      int arow = row0 + trow; if (arow >= M) arow = M-1;
      const __bf16* ga = A + (size_t)arow*K + kt*32 + ((sslot ^ f(trow))<<3);
      __builtin_amdgcn_global_load_lds((const glb_u32_t*)(const void*)ga,
          (lds_u32_t*)(void*)&As[buf][(i*64 + w*16)*32], 16, 0, 0);
      const __bf16* gb = Bt + (size_t)(col0 + trow)*K + kt*32 + ((sslot ^ f(trow))<<3);
      __builtin_amdgcn_global_load_lds((const glb_u32_t*)(const void*)gb,
          (lds_u32_t*)(void*)&Bs[buf][(i*64 + w*16)*32], 16, 0, 0);
    }
  };

  int nk = K >> 5;
  STAGE(0, 0);
  for (int kt = 0; kt < nk; ++kt){
    int cur = kt & 1;
    __syncthreads();
    if (kt+1 < nk) STAGE(cur^1, kt+1);
    bf16x8 a[4], b[4];
    #pragma unroll
    for (int m=0;m<4;m++){
      int row = wr*64 + m*16 + r16;
      a[m] = *reinterpret_cast<const bf16x8*>(&As[cur][row*32 + ((g ^ f(row))<<3)]);
    }
    #pragma unroll
    for (int n=0;n<4;n++){
      int row = wc*64 + n*16 + r16;
      b[n] = *reinterpret_cast<const bf16x8*>(&Bs[cur][row*32 + ((g ^ f(row))<<3)]);
    }
    #pragma unroll
    for (int m=0;m<4;m++)
      #pragma unroll
      for (int n=0;n<4;n++)
        acc[m][n] = __builtin_amdgcn_mfma_f32_16x16x32_bf16(a[m], b[n], acc[m][n], 0, 0, 0);
  }

  #pragma unroll
  for (int m=0;m<4;m++){
    int row_c = row0 + wr*64 + m*16 + g*4;
    #pragma unroll
    for (int n=0;n<4;n++){
      int col_c = col0 + wc*64 + n*16 + r16;
      #pragma unroll
      for (int r=0;r<4;r++)
        if (row_c + r < M) C[(size_t)(row_c+r)*N + col_c] = (__bf16)acc[m][n][r];
    }
  }
}

// ---------------- layer 1 fused v3: 1 wave per node, register-resident -------
// lane = h*8 + e (h = head 0..7, e = edge-slot 0..7). Chunk = 8 edges.
// Each lane gathers its (edge, head)-16-dim xl slice once, computes the logit
// locally, and accumulates w*xl in registers. Cross-lane: 3-shfl max per chunk
// + one final butterfly sum. No __syncthreads anywhere (waves independent).
__global__ __launch_bounds__(256) void k_fused1(
    const int* __restrict__ off, const int* __restrict__ adj,
    const int* __restrict__ esrc, int E, int N,
    const __bf16* __restrict__ H1, const float* __restrict__ att1,
    const float* __restrict__ b1, __bf16* __restrict__ out1)
{
  __shared__ float obuf[4][128];
  int wid = threadIdx.x >> 6;
  int node = blockIdx.x*4 + wid;
  int nn = min(node, N-1);
  int lane = threadIdx.x & 63;
  int h = lane >> 3, e = lane & 7;
  int begin = off[nn], deg = off[nn+1] - begin;

  // xr slice (16 dims of head h) and att slice, as f32 in regs
  float xrf[16], aw[16];
  {
    const __bf16* xp = H1 + (size_t)nn*256 + 128 + h*16;
    bf16x8 r0 = *reinterpret_cast<const bf16x8*>(xp);
    bf16x8 r1 = *reinterpret_cast<const bf16x8*>(xp + 8);
    #pragma unroll
    for (int j=0;j<8;j++){ xrf[j] = (float)r0[j]; xrf[8+j] = (float)r1[j]; }
    #pragma unroll
    for (int q=0;q<4;q++){
      float4 a4 = reinterpret_cast<const float4*>(att1 + h*16)[q];
      aw[q*4+0]=a4.x; aw[q*4+1]=a4.y; aw[q*4+2]=a4.z; aw[q*4+3]=a4.w;
    }
  }

  f32x4 acc[4];
  #pragma unroll
  for (int q=0;q<4;q++) acc[q] = (f32x4){0.f,0.f,0.f,0.f};
  float s_p = 0.f, m_run = -INFINITY;

  int nch = (deg + 7) >> 3;
  for (int ch=0; ch<nch; ch++){
    int k = ch*8 + e;
    int kc = min(k, deg-1);
    int eidx = adj[begin + kc];
    int s = (eidx < E) ? esrc[eidx] : (eidx - E);
    const __bf16* xp = H1 + (size_t)s*256 + h*16;
    bf16x8 v0 = *reinterpret_cast<const bf16x8*>(xp);
    bf16x8 v1 = *reinterpret_cast<const bf16x8*>(xp + 8);
    float xlf[16];
    #pragma unroll
    for (int j=0;j<8;j++){ xlf[j] = (float)v0[j]; xlf[8+j] = (float)v1[j]; }
    float p = 0.f;
    #pragma unroll
    for (int j=0;j<16;j++) p = fmaf(aw[j], lrelu(xlf[j] + xrf[j]), p);
    if (k >= deg) p = -INFINITY;
    // head-group max over the 8 edge-lanes
    float mc = p;
    mc = fmaxf(mc, __shfl_xor(mc,1,64));
    mc = fmaxf(mc, __shfl_xor(mc,2,64));
    mc = fmaxf(mc, __shfl_xor(mc,4,64));
    float mnew = fmaxf(m_run, mc);
    float c = __expf(m_run - mnew);          // first chunk: exp(-inf)=0
    float w = (k < deg) ? __expf(p - mnew) : 0.f;
    m_run = mnew;
    s_p = s_p*c + w;
    #pragma unroll
    for (int j=0;j<16;j++) acc[j>>2][j&3] = fmaf(w, xlf[j], acc[j>>2][j&3]*c);
  }
  // butterfly sum over the 8 edge-lanes (per head)
  #pragma unroll
  for (int mm=1;mm<8;mm<<=1){
    #pragma unroll
    for (int j=0;j<16;j++){
      float t = __shfl_xor(acc[j>>2][j&3], mm, 64);
      acc[j>>2][j&3] += t;
    }
    s_p += __shfl_xor(s_p, mm, 64);
  }
  if (e == 0){
    #pragma unroll
    for (int q=0;q<4;q++)
      *reinterpret_cast<f32x4*>(&obuf[wid][h*16 + q*4]) = acc[q];
  }
  // intra-wave LDS bounce (no barrier needed), 2 dims per lane
  float inv = 1.f/(s_p + 1e-16f);
  float2 ob = *reinterpret_cast<const float2*>(&obuf[wid][lane*2]);
  float2 bb = *reinterpret_cast<const float2*>(b1 + lane*2);
  float o0 = ob.x*inv + bb.x;
  float o1 = ob.y*inv + bb.y;
  o0 = o0 > 0.f ? o0 : expm1f(o0);
  o1 = o1 > 0.f ? o1 : expm1f(o1);
  union { __bf16 h2[2]; uint u; } pk;
  pk.h2[0] = (__bf16)o0; pk.h2[1] = (__bf16)o1;
  if (node < N)
    *reinterpret_cast<uint*>(out1 + (size_t)node*128 + lane*2) = pk.u;
}

// ---------------- layer 2 fused v3: 1 wave per node ---------------------------
// lane = q*16 + e (q = dim-quarter 0..3, e = edge-slot 0..15). Chunk = 16 edges.
__global__ __launch_bounds__(256) void k_fused2(
    const int* __restrict__ off, const int* __restrict__ adj,
    const int* __restrict__ esrc, int E, int N,
    const __bf16* __restrict__ H2, const float* __restrict__ att2,
    const float* __restrict__ b2, float* __restrict__ out)
{
  __shared__ float obuf[4][64];
  int wid = threadIdx.x >> 6;
  int node = blockIdx.x*4 + wid;
  int nn = min(node, N-1);
  int lane = threadIdx.x & 63;
  int q = lane >> 4, e = lane & 15;
  int begin = off[nn], deg = off[nn+1] - begin;

  float xrf[16], aw[16];
  {
    const __bf16* xp = H2 + (size_t)nn*128 + 64 + q*16;
    bf16x8 r0 = *reinterpret_cast<const bf16x8*>(xp);
    bf16x8 r1 = *reinterpret_cast<const bf16x8*>(xp + 8);
    #pragma unroll
    for (int j=0;j<8;j++){ xrf[j] = (float)r0[j]; xrf[8+j] = (float)r1[j]; }
    #pragma unroll
    for (int p4=0;p4<4;p4++){
      float4 a4 = reinterpret_cast<const float4*>(att2 + q*16)[p4];
      aw[p4*4+0]=a4.x; aw[p4*4+1]=a4.y; aw[p4*4+2]=a4.z; aw[p4*4+3]=a4.w;
    }
  }

  f32x4 acc[4];
  #pragma unroll
  for (int p4=0;p4<4;p4++) acc[p4] = (f32x4){0.f,0.f,0.f,0.f};
  float s_p = 0.f, m_run = -INFINITY;

  int nch = (deg + 15) >> 4;
  for (int ch=0; ch<nch; ch++){
    int k = ch*16 + e;
    int kc = min(k, deg-1);
    int eidx = adj[begin + kc];
    int s = (eidx < E) ? esrc[eidx] : (eidx - E);
    const __bf16* xp = H2 + (size_t)s*128 + q*16;
    bf16x8 v0 = *reinterpret_cast<const bf16x8*>(xp);
    bf16x8 v1 = *reinterpret_cast<const bf16x8*>(xp + 8);
    float xlf[16];
    #pragma unroll
    for (int j=0;j<8;j++){ xlf[j] = (float)v0[j]; xlf[8+j] = (float)v1[j]; }
    float p = 0.f;
    #pragma unroll
    for (int j=0;j<16;j++) p = fmaf(aw[j], lrelu(xlf[j] + xrf[j]), p);
    // sum partial dot across the 4 dim-quarters
    p += __shfl_xor(p,16,64);
    p += __shfl_xor(p,32,64);
    if (k >= deg) p = -INFINITY;
    // max over the 16 edge-lanes
    float mc = p;
    mc = fmaxf(mc, __shfl_xor(mc,1,64));
    mc = fmaxf(mc, __shfl_xor(mc,2,64));
    mc = fmaxf(mc, __shfl_xor(mc,4,64));
    mc = fmaxf(mc, __shfl_xor(mc,8,64));
    float mnew = fmaxf(m_run, mc);
    float c = __expf(m_run - mnew);
    float w = (k < deg) ? __expf(p - mnew) : 0.f;
    m_run = mnew;
    s_p = s_p*c + w;
    #pragma unroll
    for (int j=0;j<16;j++) acc[j>>2][j&3] = fmaf(w, xlf[j], acc[j>>2][j&3]*c);
  }
  #pragma unroll
  for (int mm=1;mm<16;mm<<=1){
    #pragma unroll
    for (int j=0;j<16;j++){
      float t = __shfl_xor(acc[j>>2][j&3], mm, 64);
      acc[j>>2][j&3] += t;
    }
    s_p += __shfl_xor(s_p, mm, 64);
  }
  if (e == 0){
    #pragma unroll
    for (int p4=0;p4<4;p4++)
      *reinterpret_cast<f32x4*>(&obuf[wid][q*16 + p4*4]) = acc[p4];
  }
  float inv = 1.f/(s_p + 1e-16f);
  float o = obuf[wid][lane]*inv + b2[lane];
  // log_softmax across 64 lanes
  float mx = o;
  #pragma unroll
  for (int mm=1;mm<64;mm<<=1) mx = fmaxf(mx, __shfl_xor(mx,mm,64));
  float se = __expf(o - mx);
  #pragma unroll
  for (int mm=1;mm<64;mm<<=1) se += __shfl_xor(se,mm,64);
  if (node < N)
    out[(size_t)node*64 + lane] = o - mx - __logf(se);
}

extern "C" void kernel_launch(void* const* d_in, const int* in_sizes, int n_in,
                              void* d_out, int out_size, void* d_ws, size_t ws_size,
                              hipStream_t stream)
{
  const float* x    = (const float*)d_in[0];
  const int*   ei   = (const int*)  d_in[1];
  const float* Wl1  = (const float*)d_in[2];
  const float* Wr1  = (const float*)d_in[3];
  const float* att1 = (const float*)d_in[4];
  const float* b1   = (const float*)d_in[5];
  const float* Wl2  = (const float*)d_in[6];
  const float* Wr2  = (const float*)d_in[7];
  const float* att2 = (const float*)d_in[8];
  const float* b2   = (const float*)d_in[9];
  float* out = (float*)d_out;

  const int DIN = 512;
  int N  = in_sizes[0] / DIN;     // 50000
  int E  = in_sizes[1] / 2;       // 800000
  int ET = E + N;                 // + self loops
  const int* esrc = ei;
  const int* edst = ei + E;

  char* p = (char*)d_ws;
  auto walloc = [&](size_t bytes)->void*{
    void* r = (void*)p; p += (bytes + 255) & ~(size_t)255; return r;
  };
  __bf16* xb   = (__bf16*)walloc((size_t)N*DIN*2);
  __bf16* Wt1  = (__bf16*)walloc((size_t)256*512*2);
  __bf16* Wt2  = (__bf16*)walloc((size_t)128*128*2);
  __bf16* H1   = (__bf16*)walloc((size_t)N*256*2);  // [xl1 | xr1]
  __bf16* out1 = (__bf16*)walloc((size_t)N*128*2);
  __bf16* H2   = (__bf16*)walloc((size_t)N*128*2);  // [xl2 | xr2]
  int* off    = (int*)walloc((size_t)(N+1)*4);
  int* cursor = (int*)walloc((size_t)N*4);
  int* adj    = (int*)walloc((size_t)ET*4);
  int* bsum   = (int*)walloc((size_t)256*4);

  // CSR build (hierarchical scan)
  int NB = CDIV(N,256);
  hipMemsetAsync(off, 0, (size_t)(N+1)*4, stream);
  k_count_deg<<<CDIV(ET,256),256,0,stream>>>(edst, E, ET, off);
  k_scan_a<<<NB,256,0,stream>>>(off+1, N, bsum);
  k_scan_b<<<1,256,0,stream>>>(bsum, NB);
  k_scan_c<<<NB,256,0,stream>>>(off, cursor, bsum, N);
  k_fill<<<CDIV(ET,256),256,0,stream>>>(edst, E, ET, cursor, adj);

  // prep
  int n4 = N*DIN/4;
  k_cvt_bf16<<<CDIV(n4,256),256,0,stream>>>(x, xb, n4);
  k_prep_wt<<<256,512,0,stream>>>(Wl1, Wr1, Wt1, 512, 128);
  k_prep_wt<<<128,128,0,stream>>>(Wl2, Wr2, Wt2, 128, 64);

  // Layer 1: H1[N,256] = xb[N,512] @ Wt1[256,512]^T
  dim3 g1(CDIV(N,128), 2);
  gemm_mfma<<<g1,256,0,stream>>>(xb, N, 512, Wt1, 256, H1);
  k_fused1<<<CDIV(N,4),256,0,stream>>>(off, adj, esrc, E, N, H1, att1, b1, out1);

  // Layer 2: H2[N,128] = out1[N,128] @ Wt2[128,128]^T
  dim3 g2(CDIV(N,128), 1);
  gemm_mfma<<<g2,256,0,stream>>>(out1, N, 128, Wt2, 128, H2);
  k_fused2<<<CDIV(N,4),256,0,stream>>>(off, adj, esrc, E, N, H2, att2, b2, out);
}